// Round 8
// baseline (96.084 us; speedup 1.0000x reference)
//
#include <hip/hip_runtime.h>

// Disable FMA contraction so float rounding matches the numpy reference
// op-for-op (threshold compares at 0.5 and argmax ties depend on it).
#pragma clang fp contract(off)

#define BB 32     // batch
#define NN 100    // gt boxes per image
#define PP 8732   // priors
#define BPB 128   // priors per block (j-split: 256 thr = 128 priors x 2 halves)
#define HALF 50   // gt boxes per j-half
#define CH 10     // j-chunk (5 uniform chunks of 10 -- no tail, no break)
#define LDW2 129  // padded row stride (u32): bank spread, 2-way max (free)
#define NSEG 8    // 128 priors / 16 per segment
#define NBX 69    // blocks along the prior axis (69*128 >= 8732)
#define EBX 35    // k_encode blocks (256 priors each)

// -------------------------------------------------------------------------
// Kernel 1 (j-split, DS-only inner loop): thread owns (prior pl, half h).
//   Round-7 finding: k_iou was ~3x latency-exposed because each j mixed an
//   SMEM s_load (gt box) with a DS read (area) -- SMEM completes out of
//   order on the shared lgkmcnt, forcing lgkmcnt(0) serialization per j.
//   Fix: stage all 100 gt boxes in LDS once; inner loop reads ONE
//   ds_read_b128 (broadcast, in-order -> precise lgkmcnt(N) pipelining)
//   and recomputes area_a inline with the identical expression (same bits).
//  - Column argmax: per-half strict-> argmax (ascending j), half1 merges
//    into half0 via LDS with strict > == sequential first-occurrence.
//  - Row max: verified chunk-transpose: s_iou[20][129] per chunk, phase A
//    = 20 rows x 8 segs of 16 ascending-p cols, key = (iou<<32)|~p,
//    phase B merges 8 segs -> part[b][bx][j] (USE_PART) or atomicMax.
//  - Out-of-range lanes compute the real IoU of prior PP-1: duplicates
//    tie and lose strict-> / ~p min-p tie-breaks everywhere.
//  - Exact IEEE f32 division kept -> bit-identical decisions vs reference.
// -------------------------------------------------------------------------
template <bool USE_PART>
__global__ __launch_bounds__(256) void k_iou_pass(
    const float* __restrict__ gt,        // [B,N,4] xyxy
    const float* __restrict__ priors,    // [P,4] cxcywh
    unsigned long long* __restrict__ red,   // part [B][NBX][NN] or gkey [B][N]
    unsigned char* __restrict__ m8)         // [B,P]: best_j | (bg?0x80:0)
{
    __shared__ float4 s_gt[NN];                         // 1.6 KB
    __shared__ unsigned int s_iou[2 * CH][LDW2];        // 10.3 KB
    __shared__ unsigned long long s_part[NN][NSEG + 1]; // 7.2 KB
    __shared__ unsigned long long s_cmerge[BPB];        // 1 KB

    const int b = blockIdx.y;
    const int t = threadIdx.x;
    const int h  = t >> 7;          // j-half (wave-uniform: waves 0,1 vs 2,3)
    const int pl = t & 127;         // local prior
    const int p = blockIdx.x * BPB + pl;
    const bool valid = p < PP;
    const int pc = valid ? p : (PP - 1);
    const int j0 = h * HALF;

    const float4* __restrict__ gtb =
        reinterpret_cast<const float4*>(gt) + b * NN;

    if (t < NN) s_gt[t] = gtb[t];     // coalesced float4 gather, once

    const float4 pr = reinterpret_cast<const float4*>(priors)[pc];
    const float px1 = pr.x - pr.z * 0.5f;
    const float py1 = pr.y - pr.w * 0.5f;
    const float px2 = pr.x + pr.z * 0.5f;
    const float py2 = pr.y + pr.w * 0.5f;
    const float area_b = (px2 - px1) * (py2 - py1);

    float best_ov = -1.0f;
    int best_j = 0;

    __syncthreads();   // s_gt ready

    for (int jc = 0; jc < HALF; jc += CH) {
        #pragma unroll
        for (int jj = 0; jj < CH; ++jj) {
            const int j = j0 + jc + jj;
            float4 g = s_gt[j];                        // ds_read_b128, bcast
            float area_a = (g.z - g.x) * (g.w - g.y);  // same expr as before
            float ltx = fmaxf(g.x, px1), lty = fmaxf(g.y, py1);
            float rbx = fminf(g.z, px2), rby = fminf(g.w, py2);
            float w = fmaxf(rbx - ltx, 0.0f), h2 = fmaxf(rby - lty, 0.0f);
            float inter = w * h2;
            float iou = inter / (area_a + area_b - inter + 1e-6f);
            if (iou > best_ov) { best_ov = iou; best_j = j; }
            s_iou[h * CH + jj][pl] = __float_as_uint(iou); // iou>=0: uint order
        }
        // after the LAST chunk the column state is final: publish half1's
        // (ov, j) for the merge under the same barrier that covers s_iou.
        if (jc + CH >= HALF && h == 1) {
            s_cmerge[pl] =
                ((unsigned long long)__float_as_uint(best_ov) << 32) |
                (unsigned int)best_j;
        }
        __syncthreads();

        // phase A: 20 rows (10 per half) x 8 segs of 16 ascending-p columns
        {
            const int r = t & 31;          // s_iou row (active r < 20)
            const int s = t >> 5;          // segment 0..7
            if (r < 2 * CH) {
                const int rh = (r >= CH) ? 1 : 0;
                const int rr = r - rh * CH;
                const unsigned int* row = &s_iou[r][s * 16];
                unsigned int bb = row[0];
                int bi = 0;
                #pragma unroll
                for (int i = 1; i < 16; ++i) {
                    unsigned int v = row[i];
                    if (v > bb) { bb = v; bi = i; }   // strict > = min p
                }
                int pw = blockIdx.x * BPB + s * 16 + bi;
                s_part[rh * HALF + jc + rr][s] =
                    ((unsigned long long)bb << 32) | (unsigned int)(~pw);
            }
        }
        __syncthreads();   // s_iou reusable next chunk; s_part/cmerge visible
    }

    // column merge: half1 -> half0 (strict >: lower j wins ties, matching
    // sequential first-occurrence since all half0 js < half1 js)
    if (h == 0) {
        unsigned long long k1 = s_cmerge[pl];
        float ov1 = __uint_as_float((unsigned int)(k1 >> 32));
        int   j1  = (int)(k1 & 0xFFFFFFFFull);
        if (ov1 > best_ov) { best_ov = ov1; best_j = j1; }
        if (valid) {
            m8[b * PP + p] =
                (unsigned char)(best_j | ((best_ov < 0.5f) ? 0x80 : 0));
        }
    }

    // phase B: merge 8 segment partials per gt; plain store (or atomic)
    if (t < NN) {
        unsigned long long best = s_part[t][0];
        #pragma unroll
        for (int s = 1; s < NSEG; ++s) {
            unsigned long long k = s_part[t][s];
            if (k > best) best = k;                   // ~p breaks iou ties
        }
        if (USE_PART) {
            red[((size_t)b * NBX + blockIdx.x) * NN + t] = best;
        } else {
            atomicMax(&red[b * NN + t], best);
        }
    }
}

// -------------------------------------------------------------------------
// Kernel 2: reduce the 69 per-block row keys (USE_PART) or read gkey,
// scatter forced matches into LDS (max j = last-write-wins, matching the
// reference scatter), then encode. 256 priors per block (35 blocks).
// -------------------------------------------------------------------------
template <bool USE_PART>
__global__ __launch_bounds__(256) void k_encode(
    const float* __restrict__ gt,        // [B,N,4]
    const int*   __restrict__ labels,    // [B,N]
    const float* __restrict__ priors,    // [P,4]
    const unsigned long long* __restrict__ red,   // part or gkey
    const unsigned char* __restrict__ m8,         // [B,P]
    float* __restrict__ loc_out,         // [B,P,4]
    float* __restrict__ conf_out)        // [B,P]
{
    __shared__ int s_forced[256];        // local p -> forced gt j (-1 none)

    const int b = blockIdx.y;
    const int t = threadIdx.x;
    const int p = blockIdx.x * 256 + t;

    s_forced[t] = -1;
    __syncthreads();
    if (t < NN) {
        unsigned long long best;
        if (USE_PART) {
            const unsigned long long* q = red + (size_t)b * NBX * NN + t;
            best = q[0];
            #pragma unroll 4
            for (int bx = 1; bx < NBX; ++bx) {
                unsigned long long k = q[(size_t)bx * NN];
                if (k > best) best = k;
            }
        } else {
            best = red[b * NN + t];
        }
        int kp = (int)~(unsigned int)(best & 0xFFFFFFFFull);
        int lp = kp - blockIdx.x * 256;
        if ((unsigned)lp < 256u) atomicMax(&s_forced[lp], t);
    }
    __syncthreads();

    if (p >= PP) return;
    const int forced_j = s_forced[t];

    const unsigned char m = m8[b * PP + p];
    const int j    = (forced_j >= 0) ? forced_j : (m & 0x7f);
    const int lab  = labels[b * NN + j];
    const int conf = (forced_j < 0 && (m & 0x80)) ? 0 : (lab + 1);

    const float4 pr = reinterpret_cast<const float4*>(priors)[p];
    const float4 g  = reinterpret_cast<const float4*>(gt)[b * NN + j];
    const float mcx = (g.x + g.z) * 0.5f;
    const float mcy = (g.y + g.w) * 0.5f;
    const float mw  = fmaxf(g.z - g.x, 1e-6f);
    const float mh  = fmaxf(g.w - g.y, 1e-6f);
    const float gcx = (mcx - pr.x) / (0.1f * pr.z);
    const float gcy = (mcy - pr.y) / (0.1f * pr.w);
    const float gw  = logf(mw / pr.z) / 0.2f;
    const float gh  = logf(mh / pr.w) / 0.2f;

    reinterpret_cast<float4*>(loc_out)[b * PP + p] =
        make_float4(gcx, gcy, gw, gh);
    conf_out[b * PP + p] = (float)conf;
}

extern "C" void kernel_launch(void* const* d_in, const int* in_sizes, int n_in,
                              void* d_out, int out_size, void* d_ws, size_t ws_size,
                              hipStream_t stream) {
    const float* gt     = (const float*)d_in[0];  // [32,100,4] f32
    const int*   labels = (const int*)  d_in[1];  // [32,100] i32
    const float* priors = (const float*)d_in[2];  // [8732,4] f32

    float* loc  = (float*)d_out;                         // [32,8732,4]
    float* conf = (float*)d_out + (size_t)BB * PP * 4;   // [32,8732]

    const size_t part_bytes = (size_t)BB * NBX * NN * 8;   // 1,766,400
    const size_t m8_bytes   = (size_t)BB * PP;             // 279,424
    dim3 grid_i(NBX, BB);
    dim3 grid_e(EBX, BB);

    if (ws_size >= part_bytes + m8_bytes) {
        // atomic-free path: per-block partial keys, no memset dispatch
        unsigned long long* part = (unsigned long long*)d_ws;
        unsigned char* m8 = (unsigned char*)d_ws + part_bytes;
        k_iou_pass<true><<<grid_i, 256, 0, stream>>>(gt, priors, part, m8);
        k_encode<true><<<grid_e, 256, 0, stream>>>(gt, labels, priors, part,
                                                   m8, loc, conf);
    } else {
        // fallback: gkey + atomicMax (needs zeroed keys)
        unsigned long long* gkey = (unsigned long long*)d_ws;        // [32,100]
        unsigned char* m8 = (unsigned char*)d_ws + (size_t)BB * NN * 8;
        hipMemsetAsync(gkey, 0, (size_t)BB * NN * 8, stream);
        k_iou_pass<false><<<grid_i, 256, 0, stream>>>(gt, priors, gkey, m8);
        k_encode<false><<<grid_e, 256, 0, stream>>>(gt, labels, priors, gkey,
                                                    m8, loc, conf);
    }
}